// Round 11
// baseline (187.733 us; speedup 1.0000x reference)
//
#include <hip/hip_runtime.h>
#include <stdint.h>

typedef __attribute__((ext_vector_type(16))) float f32x16;
typedef __attribute__((ext_vector_type(8))) _Float16 f16x8;
typedef __attribute__((ext_vector_type(8))) unsigned short u16x8;

#define HIDDEN 1024
#define SEQ 2048
#define NB 4

__device__ inline unsigned short f2h_bits(float f) {
    _Float16 h = (_Float16)f;
    return __builtin_bit_cast(unsigned short, h);
}
__device__ inline float h2f(unsigned short u) {
    return (float)__builtin_bit_cast(_Float16, u);
}

__device__ inline void gload16(const void* g, void* l) {
    __builtin_amdgcn_global_load_lds(
        (const __attribute__((address_space(1))) unsigned int*)g,
        (__attribute__((address_space(3))) unsigned int*)l,
        16, 0, 0);
}

template<int N> __device__ inline void waitvm() {
    if constexpr (N == 0) asm volatile("s_waitcnt vmcnt(0)" ::: "memory");
    else if constexpr (N == 3) asm volatile("s_waitcnt vmcnt(3)" ::: "memory");
    else if constexpr (N == 4) asm volatile("s_waitcnt vmcnt(4)" ::: "memory");
    else if constexpr (N == 6) asm volatile("s_waitcnt vmcnt(6)" ::: "memory");
    else if constexpr (N == 8) asm volatile("s_waitcnt vmcnt(8)" ::: "memory");
    else static_assert(N == 0, "bad vmcnt");
}
template<int N> __device__ inline void waitlgkm() {
    if constexpr (N == 0) asm volatile("s_waitcnt lgkmcnt(0)" ::: "memory");
    else if constexpr (N == 2) asm volatile("s_waitcnt lgkmcnt(2)" ::: "memory");
    else if constexpr (N == 3) asm volatile("s_waitcnt lgkmcnt(3)" ::: "memory");
    else if constexpr (N == 4) asm volatile("s_waitcnt lgkmcnt(4)" ::: "memory");
    else if constexpr (N == 5) asm volatile("s_waitcnt lgkmcnt(5)" ::: "memory");
    else if constexpr (N == 6) asm volatile("s_waitcnt lgkmcnt(6)" ::: "memory");
    else static_assert(N == 0, "bad lgkmcnt");
}

// ============ R7-rhythm pipelined GEMM, 32x32x16 MFMA ============
// C[M,N] = A[M,K] @ Bt[N,K]^T (+bias). fp16 in, f32 accum.
// Wave grid WM x WN; wave tile (BM/WM) x (BN/WN) built from 32x32 frags
// (MR2 x NR2 per wave, 2 kk-halves per K=32 slice).
// LDS ring of 4 slice-slots; swizzle phys-16B-slot = logical ^ ((row>>1)&3)
// (0 conflicts measured R4-R10). Stage distance 3; counted vmcnt gate at the
// top of each slice (2LP steady, LP/0 at tail) — R7's best-measured rhythm.
// Counted lgkm: first (MR2+NR2) reads gate kk=0 MFMA; the kk=1 reads retire
// under the kk=0 MFMA burst.
// A-frag (32x32x16 f16): lane l holds A[m=l&31][k=(l>>5)*8+j]; B same on n.
// C/D: col=lane&31, row=(reg&3)+8*(reg>>2)+4*(lane>>5)  [m74/m101 verified].
// T1: bijective XCD block swizzle (requires nwg % 8 == 0).
// BIAS_MODE: 0 none, 1 bias[col], 2 bias[row].
template<int BM, int BN, int WM, int WN, int BIAS_MODE, bool OUT_F16, int MINW>
__global__ __launch_bounds__(WM * WN * 64, MINW) void gemm32(
    const unsigned short* __restrict__ A, int lda,
    const unsigned short* __restrict__ Bt, int ldb,
    const float* __restrict__ bias,
    void* __restrict__ Cptr, int ldc, int K,
    long long aBatch, long long bBatch, long long cBatch)
{
    constexpr int THREADS = WM * WN * 64;
    constexpr int MR2 = BM / (WM * 32);   // 32-row frags per wave
    constexpr int NR2 = BN / (WN * 32);   // 32-col frags per wave
    constexpr int FIRST = MR2 + NR2;      // reads needed for kk=0
    constexpr int LA = 4 * BM / THREADS;
    constexpr int LB = 4 * BN / THREADS;
    constexpr int LP = LA + LB;
    constexpr int ASLICE = BM * 32;
    constexpr int BSLICE = BN * 32;
    constexpr int BOFF = 4 * ASLICE;

    extern __shared__ unsigned short lds[];

    const int tid = threadIdx.x, lane = tid & 63, wave = tid >> 6;
    const int wr = wave / WN, wc = wave % WN;
    const int l31 = lane & 31, l5 = lane >> 5;

    // T1 XCD-bijective block swizzle over the flat grid
    const int gx = gridDim.x, gy = gridDim.y;
    const int nwg = gx * gy * gridDim.z;
    const int id = (blockIdx.z * gy + blockIdx.y) * gx + blockIdx.x;
    const int id2 = (id & 7) * (nwg >> 3) + (id >> 3);
    const int bx = id2 % gx;
    const int by = (id2 / gx) % gy;
    const long long bz = id2 / (gx * gy);

    const unsigned short* Ab = A + bz * aBatch + (long long)(by * BM) * lda;
    const unsigned short* Bb = Bt + bz * bBatch + (long long)(bx * BN) * ldb;

    // staging: chunk c = i*THREADS+tid; row=c>>2, phys slot=c&3,
    // logical slot = phys ^ ((row>>1)&3) -> pre-inverse-swizzled source
    const unsigned short* sA[LA]; int dA[LA];
    #pragma unroll
    for (int i = 0; i < LA; ++i) {
        int c = i * THREADS + tid; int r = c >> 2; int ls = (c & 3) ^ ((r >> 1) & 3);
        sA[i] = Ab + (long long)r * lda + ls * 8;
        dA[i] = (i * THREADS + wave * 64) * 16;
    }
    const unsigned short* sB[LB]; int dB[LB];
    #pragma unroll
    for (int i = 0; i < LB; ++i) {
        int c = i * THREADS + tid; int r = c >> 2; int ls = (c & 3) ^ ((r >> 1) & 3);
        sB[i] = Bb + (long long)r * ldb + ls * 8;
        dB[i] = (i * THREADS + wave * 64) * 16;
    }

    auto stage = [&](int q) {   // stage slice q -> ring slot q&3
        int slot = q & 3, kof = q * 32;
        #pragma unroll
        for (int i = 0; i < LA; ++i)
            gload16(sA[i] + kof, (char*)lds + slot * (ASLICE * 2) + dA[i]);
        #pragma unroll
        for (int i = 0; i < LB; ++i)
            gload16(sB[i] + kof, (char*)lds + (BOFF + slot * BSLICE) * 2 + dB[i]);
    };

    const int NPAIR = K / 32;
    stage(0); stage(1); stage(2);

    f32x16 acc[MR2][NR2] = {};

    for (int p = 0; p < NPAIR; ++p) {
        // gate: slice p landed; later slices stay in flight (R7 rhythm)
        if (p == NPAIR - 1) waitvm<0>();
        else if (p == NPAIR - 2) waitvm<LP>();
        else waitvm<2 * LP>();
        __builtin_amdgcn_s_barrier();
        __builtin_amdgcn_sched_barrier(0);

        const int slot = p & 3;
        const unsigned short* as = lds + slot * ASLICE;
        const unsigned short* bs = lds + BOFF + slot * BSLICE;

        f16x8 af[MR2][2], bf[NR2][2];
        // kk=0 reads (FIRST of them gate phase 0)
        #pragma unroll
        for (int n = 0; n < NR2; ++n) {
            int r = wc * (BN / WN) + n * 32 + l31;
            int es = l5 ^ ((r >> 1) & 3);
            bf[n][0] = *(const f16x8*)&bs[r * 32 + es * 8];
        }
        #pragma unroll
        for (int m = 0; m < MR2; ++m) {
            int r = wr * (BM / WM) + m * 32 + l31;
            int es = l5 ^ ((r >> 1) & 3);
            af[m][0] = *(const f16x8*)&as[r * 32 + es * 8];
        }
        if (p + 3 < NPAIR) stage(p + 3);   // slot (p+3)&3 == (p-1)&3: readers done
        // kk=1 reads retire under the kk=0 MFMA burst
        #pragma unroll
        for (int n = 0; n < NR2; ++n) {
            int r = wc * (BN / WN) + n * 32 + l31;
            int es = (2 + l5) ^ ((r >> 1) & 3);
            bf[n][1] = *(const f16x8*)&bs[r * 32 + es * 8];
        }
        #pragma unroll
        for (int m = 0; m < MR2; ++m) {
            int r = wr * (BM / WM) + m * 32 + l31;
            int es = (2 + l5) ^ ((r >> 1) & 3);
            af[m][1] = *(const f16x8*)&as[r * 32 + es * 8];
        }

        waitlgkm<FIRST>();                 // kk=0 frags ready; kk=1 in flight
        __builtin_amdgcn_sched_barrier(0);
        __builtin_amdgcn_s_setprio(1);
        #pragma unroll
        for (int m = 0; m < MR2; ++m)
            #pragma unroll
            for (int n = 0; n < NR2; ++n)
                acc[m][n] = __builtin_amdgcn_mfma_f32_32x32x16_f16(af[m][0], bf[n][0], acc[m][n], 0, 0, 0);
        __builtin_amdgcn_s_setprio(0);
        __builtin_amdgcn_sched_barrier(0);
        waitlgkm<0>();
        __builtin_amdgcn_sched_barrier(0);
        __builtin_amdgcn_s_setprio(1);
        #pragma unroll
        for (int m = 0; m < MR2; ++m)
            #pragma unroll
            for (int n = 0; n < NR2; ++n)
                acc[m][n] = __builtin_amdgcn_mfma_f32_32x32x16_f16(af[m][1], bf[n][1], acc[m][n], 0, 0, 0);
        __builtin_amdgcn_s_setprio(0);
    }

    // epilogue: C/D col=lane&31, row=(reg&3)+8*(reg>>2)+4*(lane>>5)
    const int row0 = by * BM + wr * (BM / WM);
    const int col0 = bx * BN + wc * (BN / WN);
    #pragma unroll
    for (int m = 0; m < MR2; ++m)
        #pragma unroll
        for (int n = 0; n < NR2; ++n)
            #pragma unroll
            for (int reg = 0; reg < 16; ++reg) {
                int r = row0 + m * 32 + (reg & 3) + 8 * (reg >> 2) + 4 * l5;
                int c = col0 + n * 32 + l31;
                float v = acc[m][n][reg];
                if constexpr (BIAS_MODE == 1) v += bias[c];
                if constexpr (BIAS_MODE == 2) v += bias[r];
                if constexpr (OUT_F16)
                    ((unsigned short*)Cptr + bz * cBatch)[(long long)r * ldc + c] = f2h_bits(v);
                else
                    ((float*)Cptr + bz * cBatch)[(long long)r * ldc + c] = v;
            }
}

// ===================== small kernels =====================
__global__ __launch_bounds__(256) void cvt_f32_f16(const float* __restrict__ in,
                                                   unsigned short* __restrict__ out, int n8)
{
    int i = blockIdx.x * blockDim.x + threadIdx.x;
    if (i >= n8) return;
    const float4* p = (const float4*)in + (long long)i * 2;
    float4 a = p[0], b = p[1];
    ushort4 o0, o1;
    o0.x = f2h_bits(a.x); o0.y = f2h_bits(a.y); o0.z = f2h_bits(a.z); o0.w = f2h_bits(a.w);
    o1.x = f2h_bits(b.x); o1.y = f2h_bits(b.y); o1.z = f2h_bits(b.z); o1.w = f2h_bits(b.w);
    ushort4* o = (ushort4*)out + (long long)i * 2;
    o[0] = o0; o[1] = o1;
}

// out[z][c][r] = (fp16) in[z][r][c] for 1024x1024 f32 weights, z=3
__global__ void transpose_cvt3(const float* __restrict__ in, unsigned short* __restrict__ out)
{
    __shared__ unsigned short t[32][33];
    const long long z = blockIdx.z;
    const float* inz = in + z * HIDDEN * HIDDEN;           // contiguous W's? no — separate ptrs
    (void)inz;
    const int bx = blockIdx.x * 32;
    const int by = blockIdx.y * 32;
    const int xT = threadIdx.x, yT = threadIdx.y;  // block (32,8)
    // in pointers are not contiguous; handled by caller passing base of each — see launch
    const float* src = in;
    unsigned short* dst = out;
    #pragma unroll
    for (int i = 0; i < 32; i += 8)
        t[yT + i][xT] = f2h_bits(src[(long long)(by + yT + i) * HIDDEN + bx + xT]);
    __syncthreads();
    #pragma unroll
    for (int i = 0; i < 32; i += 8)
        dst[(long long)(bx + yT + i) * HIDDEN + by + xT] = t[xT][yT + i];
}

__global__ void transpose_cvt(const float* __restrict__ in, unsigned short* __restrict__ out,
                              int R, int C)
{
    __shared__ unsigned short t[32][33];
    const int bx = blockIdx.x * 32;
    const int by = blockIdx.y * 32;
    const int xT = threadIdx.x, yT = threadIdx.y;  // block (32,8)
    #pragma unroll
    for (int i = 0; i < 32; i += 8)
        t[yT + i][xT] = f2h_bits(in[(long long)(by + yT + i) * C + bx + xT]);
    __syncthreads();
    #pragma unroll
    for (int i = 0; i < 32; i += 8)
        out[(long long)(bx + yT + i) * R + by + xT] = t[xT][yT + i];
}

__global__ void concat_bias2(const float* __restrict__ bq, const float* __restrict__ bk,
                             float* __restrict__ cb)
{
    int i = threadIdx.x;  // 1024 threads
    cb[i] = bq[i];
    cb[HIDDEN + i] = bk[i];
}

// One block (256 threads) per row of 2048 fp16 scores; P fp16 in place.
__global__ __launch_bounds__(256) void softmax_h(unsigned short* __restrict__ S)
{
    const int tid = threadIdx.x;
    unsigned short* row = S + (long long)blockIdx.x * SEQ;
    u16x8 hv = *(const u16x8*)&row[tid * 8];
    float vv[8];
    #pragma unroll
    for (int j = 0; j < 8; ++j) vv[j] = h2f(hv[j]);

    float mx = vv[0];
    #pragma unroll
    for (int j = 1; j < 8; ++j) mx = fmaxf(mx, vv[j]);
    #pragma unroll
    for (int o = 32; o > 0; o >>= 1) mx = fmaxf(mx, __shfl_xor(mx, o));
    __shared__ float redm[4], reds[4];
    if ((tid & 63) == 0) redm[tid >> 6] = mx;
    __syncthreads();
    mx = fmaxf(fmaxf(redm[0], redm[1]), fmaxf(redm[2], redm[3]));

    float ev[8], sum = 0.f;
    #pragma unroll
    for (int j = 0; j < 8; ++j) { ev[j] = __expf(vv[j] - mx); sum += ev[j]; }
    #pragma unroll
    for (int o = 32; o > 0; o >>= 1) sum += __shfl_xor(sum, o);
    if ((tid & 63) == 0) reds[tid >> 6] = sum;
    __syncthreads();
    sum = reds[0] + reds[1] + reds[2] + reds[3];
    float inv = 1.0f / sum;

    u16x8 ov;
    #pragma unroll
    for (int j = 0; j < 8; ++j) ov[j] = f2h_bits(ev[j] * inv);
    *(u16x8*)&row[tid * 8] = ov;
}

// ===================== launch =====================
extern "C" void kernel_launch(void* const* d_in, const int* in_sizes, int n_in,
                              void* d_out, int out_size, void* d_ws, size_t ws_size,
                              hipStream_t stream)
{
    (void)in_sizes; (void)n_in; (void)out_size; (void)ws_size;
    const float* x  = (const float*)d_in[0];
    const float* Wq = (const float*)d_in[1];
    const float* bq = (const float*)d_in[2];
    const float* Wk = (const float*)d_in[3];
    const float* bk = (const float*)d_in[4];
    const float* Wv = (const float*)d_in[5];
    const float* bv = (const float*)d_in[6];
    float* out = (float*)d_out;

    // variants: proj/S 256x256 (8 waves, 128KB); vt 128x256 (96KB); O 256x128 (96KB)
    (void)hipFuncSetAttribute(reinterpret_cast<const void*>(&gemm32<256, 256, 2, 4, 1, true, 2>),
                              hipFuncAttributeMaxDynamicSharedMemorySize, 131072);
    (void)hipFuncSetAttribute(reinterpret_cast<const void*>(&gemm32<256, 256, 2, 4, 0, true, 2>),
                              hipFuncAttributeMaxDynamicSharedMemorySize, 131072);
    (void)hipFuncSetAttribute(reinterpret_cast<const void*>(&gemm32<128, 256, 2, 4, 2, true, 2>),
                              hipFuncAttributeMaxDynamicSharedMemorySize, 98304);
    (void)hipFuncSetAttribute(reinterpret_cast<const void*>(&gemm32<256, 128, 2, 4, 0, false, 2>),
                              hipFuncAttributeMaxDynamicSharedMemorySize, 98304);

    char* ws = (char*)d_ws;
    const long long MTOT = (long long)NB * SEQ;  // 8192

    // Layout (83.9 MB):
    //  [0, 33.55M)      qk   [8192][2048] fp16
    //  [33.55, 50.33M)  vt   [1024][8192] fp16
    //  [50.33, 83.89M)  S region: 4 x [2048][2048] fp16 (all batches).
    //    During projections it holds wt (6.29M) + cb + xh (16.78M), dead after vt.
    unsigned short* qk = (unsigned short*)ws;
    unsigned short* vt = (unsigned short*)(ws + (size_t)MTOT * 2048 * 2);
    char* sreg = ws + (size_t)MTOT * 2048 * 2 + (size_t)HIDDEN * MTOT * 2;
    unsigned short* wt = (unsigned short*)sreg;
    float* cb = (float*)(sreg + (size_t)3 * HIDDEN * HIDDEN * 2);
    unsigned short* xh = (unsigned short*)(sreg + (size_t)3 * HIDDEN * HIDDEN * 2 + 8192);
    unsigned short* S = (unsigned short*)sreg;

    {
        int n8 = (int)(MTOT * HIDDEN / 8);
        cvt_f32_f16<<<dim3((n8 + 255) / 256), 256, 0, stream>>>(x, xh, n8);
    }
    dim3 tb(32, 8), tg(HIDDEN / 32, HIDDEN / 32);
    transpose_cvt<<<tg, tb, 0, stream>>>(Wq, wt,                       HIDDEN, HIDDEN);
    transpose_cvt<<<tg, tb, 0, stream>>>(Wk, wt +     HIDDEN * HIDDEN, HIDDEN, HIDDEN);
    transpose_cvt<<<tg, tb, 0, stream>>>(Wv, wt + 2 * HIDDEN * HIDDEN, HIDDEN, HIDDEN);
    concat_bias2<<<1, 1024, 0, stream>>>(bq, bk, cb);

    // qk[8192][2048] = xh @ [Wq|Wk] + [bq|bk]   (256 blocks)
    gemm32<256, 256, 2, 4, 1, true, 2><<<dim3(2048 / 256, (unsigned)(MTOT / 256), 1), 512, 131072, stream>>>(
        xh, HIDDEN, wt, HIDDEN, cb, qk, 2048, HIDDEN, 0, 0, 0);

    // vt[1024][8192] = Wv^T @ xh^T + bv (row bias)   (256 blocks)
    gemm32<128, 256, 2, 4, 2, true, 2><<<dim3((unsigned)(MTOT / 256), HIDDEN / 128, 1), 512, 98304, stream>>>(
        wt + 2 * HIDDEN * HIDDEN, HIDDEN, xh, HIDDEN, bv, vt, (int)MTOT, HIDDEN, 0, 0, 0);

    // S[b][2048][2048] fp16 = q @ k^T   (z=4, 256 blocks)
    gemm32<256, 256, 2, 4, 0, true, 2><<<dim3(SEQ / 256, SEQ / 256, NB), 512, 131072, stream>>>(
        qk, 2048, qk + HIDDEN, 2048, nullptr, S, SEQ, HIDDEN,
        (long long)SEQ * 2048, (long long)SEQ * 2048, (long long)SEQ * SEQ);

    // softmax all rows, P fp16 in place
    softmax_h<<<dim3(NB * SEQ), 256, 0, stream>>>(S);

    // out[b] = P @ vt^T  (z=4, 512 blocks, f32 straight to d_out)
    gemm32<256, 128, 2, 4, 0, false, 2><<<dim3(HIDDEN / 128, SEQ / 256, NB), 512, 98304, stream>>>(
        S, SEQ, vt, (int)MTOT, nullptr, out, HIDDEN, SEQ,
        (long long)SEQ * SEQ, (long long)SEQ, (long long)SEQ * HIDDEN);
}

// Round 12
// 180.803 us; speedup vs baseline: 1.0383x; 1.0383x over previous
//
#include <hip/hip_runtime.h>
#include <stdint.h>

typedef __attribute__((ext_vector_type(4))) float f32x4;
typedef __attribute__((ext_vector_type(8))) _Float16 f16x8;
typedef __attribute__((ext_vector_type(8))) unsigned short u16x8;

#define HIDDEN 1024
#define SEQ 2048
#define NB 4

__device__ inline unsigned short f2h_bits(float f) {
    _Float16 h = (_Float16)f;
    return __builtin_bit_cast(unsigned short, h);
}
__device__ inline float h2f(unsigned short u) {
    return (float)__builtin_bit_cast(_Float16, u);
}

__device__ inline void gload16(const void* g, void* l) {
    __builtin_amdgcn_global_load_lds(
        (const __attribute__((address_space(1))) unsigned int*)g,
        (__attribute__((address_space(3))) unsigned int*)l,
        16, 0, 0);
}

template<int N> __device__ inline void waitvm() {
    if constexpr (N == 0) asm volatile("s_waitcnt vmcnt(0)" ::: "memory");
    else if constexpr (N == 3) asm volatile("s_waitcnt vmcnt(3)" ::: "memory");
    else if constexpr (N == 4) asm volatile("s_waitcnt vmcnt(4)" ::: "memory");
    else if constexpr (N == 6) asm volatile("s_waitcnt vmcnt(6)" ::: "memory");
    else if constexpr (N == 8) asm volatile("s_waitcnt vmcnt(8)" ::: "memory");
    else static_assert(N == 0, "bad vmcnt");
}
__device__ inline void waitlgkm0() { asm volatile("s_waitcnt lgkmcnt(0)" ::: "memory"); }

// ============ m201-faithful 4-phase/K-tile GEMM ============
// C[M,N] = A[M,K] @ Bt[N,K]^T (+bias). fp16 in, f32 accum.
// Wave grid WM x WN; wave tile (BM/WM) x (BN/WN). K-tile = 64 = 2 k-slices
// of 32; LDS ring of 4 slices per operand (slot = slice & 3); swizzle
// phys-16B-slot = logical ^ ((row>>1)&3) (0 conflicts, verified R4-R10).
// Per tile, 4 phases = (m-half x k-half) quadrants, each:
//   {reads for this quadrant (B reused across m-half phases); stage ONE
//    half-tile; s_barrier; lgkmcnt(0); setprio(1) 16-MFMA setprio(0);
//    [gate vmcnt on ph1/ph3]; s_barrier}
// Stage schedule: ph0 ->(t+1,A k1), ph1 ->(t+1,B k1), ph2 ->(t+2,A k0),
// ph3 ->(t+2,B k0). WAR-safe: each target slot's readers finished a phase
// earlier. Gates (drain-own-then-publish) leave 2A+2B half-tiles in flight:
// SN steady; tail t=NT-1: ph1 -> 0; t=NT-2 ph3 -> TN; t=NT-1 ph3 -> none.
// T1: bijective XCD block swizzle (requires nwg % 8 == 0).
// BIAS_MODE: 0 none, 1 bias[col], 2 bias[row].
template<int BM, int BN, int WM, int WN, int BIAS_MODE, bool OUT_F16>
__global__ __launch_bounds__(WM * WN * 64, 2) void gemm4p(
    const unsigned short* __restrict__ A, int lda,
    const unsigned short* __restrict__ Bt, int ldb,
    const float* __restrict__ bias,
    void* __restrict__ Cptr, int ldc, int K,
    long long aBatch, long long bBatch, long long cBatch)
{
    constexpr int THREADS = WM * WN * 64;
    constexpr int MR = BM / (WM * 16);
    constexpr int NR = BN / (WN * 16);
    constexpr int MH2 = MR / 2;
    constexpr int LAH = 4 * BM / THREADS;   // gloads/thread per A half-tile
    constexpr int LBH = 4 * BN / THREADS;
    constexpr int SN = 2 * (LAH + LBH);     // steady gate (leave 2A+2B halves)
    constexpr int TN = LAH + LBH;           // tail gate
    constexpr int ASLICE = BM * 32;         // halfs per A k-slice
    constexpr int BSLICE = BN * 32;
    constexpr int BOFF = 4 * ASLICE;

    extern __shared__ unsigned short lds[];

    const int tid = threadIdx.x, lane = tid & 63, wave = tid >> 6;
    const int wr = wave / WN, wc = wave % WN;
    const int fr = lane & 15, fq = lane >> 4;

    // T1 XCD-bijective block swizzle over the flat grid
    const int gx = gridDim.x, gy = gridDim.y;
    const int nwg = gx * gy * gridDim.z;
    const int id = (blockIdx.z * gy + blockIdx.y) * gx + blockIdx.x;
    const int id2 = (id & 7) * (nwg >> 3) + (id >> 3);
    const int bx = id2 % gx;
    const int by = (id2 / gx) % gy;
    const long long bz = id2 / (gx * gy);

    const unsigned short* Ab = A + bz * aBatch + (long long)(by * BM) * lda;
    const unsigned short* Bb = Bt + bz * bBatch + (long long)(bx * BN) * ldb;

    // staging: chunk c = i*THREADS+tid; row=c>>2, phys slot=c&3,
    // logical slot = phys ^ ((row>>1)&3) -> pre-inverse-swizzled source
    const unsigned short* sA[LAH]; int dA[LAH];
    #pragma unroll
    for (int i = 0; i < LAH; ++i) {
        int c = i * THREADS + tid; int r = c >> 2; int ls = (c & 3) ^ ((r >> 1) & 3);
        sA[i] = Ab + (long long)r * lda + ls * 8;
        dA[i] = (i * THREADS + wave * 64) * 16;
    }
    const unsigned short* sB[LBH]; int dB[LBH];
    #pragma unroll
    for (int i = 0; i < LBH; ++i) {
        int c = i * THREADS + tid; int r = c >> 2; int ls = (c & 3) ^ ((r >> 1) & 3);
        sB[i] = Bb + (long long)r * ldb + ls * 8;
        dB[i] = (i * THREADS + wave * 64) * 16;
    }

    auto stageA = [&](int q) {   // A k-slice q -> ring slot q&3
        int slot = q & 3, kof = q * 32;
        #pragma unroll
        for (int i = 0; i < LAH; ++i)
            gload16(sA[i] + kof, (char*)lds + slot * (ASLICE * 2) + dA[i]);
    };
    auto stageB = [&](int q) {
        int slot = q & 3, kof = q * 32;
        #pragma unroll
        for (int i = 0; i < LBH; ++i)
            gload16(sB[i] + kof, (char*)lds + (BOFF + slot * BSLICE) * 2 + dB[i]);
    };

    const int NT = K / 64;
    const int NS = 2 * NT;                   // k-slices
    // prologue: 6 half-tiles in flight: A0,B0,A1,B1,A2,B2
    stageA(0); stageB(0); stageA(1); stageB(1); stageA(2); stageB(2);
    waitvm<SN>();                            // slices 0 (A+B) landed
    __builtin_amdgcn_s_barrier();

    f32x4 acc[MR][NR] = {};
    f16x8 afL[MH2], afH[MH2], bf[NR];

    for (int t = 0; t < NT; ++t) {
        const int s0 = 2 * t, s1 = 2 * t + 1;
        const unsigned short* as0 = lds + (s0 & 3) * ASLICE;
        const unsigned short* bs0 = lds + BOFF + (s0 & 3) * BSLICE;
        const unsigned short* as1 = lds + (s1 & 3) * ASLICE;
        const unsigned short* bs1 = lds + BOFF + (s1 & 3) * BSLICE;

        // ---------- ph0: kk0, m-rows [0, MH2) ----------
        #pragma unroll
        for (int n = 0; n < NR; ++n) {
            int r = wc * (BN / WN) + n * 16 + fr;
            int es = fq ^ ((r >> 1) & 3);
            bf[n] = *(const f16x8*)&bs0[r * 32 + es * 8];
        }
        #pragma unroll
        for (int i = 0; i < MH2; ++i) {
            int r = wr * (BM / WM) + i * 16 + fr;
            int es = fq ^ ((r >> 1) & 3);
            afL[i] = *(const f16x8*)&as0[r * 32 + es * 8];
        }
        if (s0 + 3 < NS) stageA(s0 + 3);
        __builtin_amdgcn_s_barrier();
        waitlgkm0();
        __builtin_amdgcn_sched_barrier(0);
        __builtin_amdgcn_s_setprio(1);
        #pragma unroll
        for (int i = 0; i < MH2; ++i)
            #pragma unroll
            for (int n = 0; n < NR; ++n)
                acc[i][n] = __builtin_amdgcn_mfma_f32_16x16x32_f16(afL[i], bf[n], acc[i][n], 0, 0, 0);
        __builtin_amdgcn_s_setprio(0);
        __builtin_amdgcn_s_barrier();

        // ---------- ph1: kk0, m-rows [MH2, MR) ----------
        #pragma unroll
        for (int i = 0; i < MH2; ++i) {
            int r = wr * (BM / WM) + (MH2 + i) * 16 + fr;
            int es = fq ^ ((r >> 1) & 3);
            afH[i] = *(const f16x8*)&as0[r * 32 + es * 8];
        }
        if (s0 + 3 < NS) stageB(s0 + 3);
        __builtin_amdgcn_s_barrier();
        waitlgkm0();
        __builtin_amdgcn_sched_barrier(0);
        __builtin_amdgcn_s_setprio(1);
        #pragma unroll
        for (int i = 0; i < MH2; ++i)
            #pragma unroll
            for (int n = 0; n < NR; ++n)
                acc[MH2 + i][n] = __builtin_amdgcn_mfma_f32_16x16x32_f16(afH[i], bf[n], acc[MH2 + i][n], 0, 0, 0);
        __builtin_amdgcn_s_setprio(0);
        if (t < NT - 1) waitvm<SN>();       // drain (t,Ak1),(t,Bk1) for ph2/ph3
        else waitvm<0>();
        __builtin_amdgcn_s_barrier();        // publish

        // ---------- ph2: kk1, m-rows [0, MH2) ----------
        #pragma unroll
        for (int n = 0; n < NR; ++n) {
            int r = wc * (BN / WN) + n * 16 + fr;
            int es = fq ^ ((r >> 1) & 3);
            bf[n] = *(const f16x8*)&bs1[r * 32 + es * 8];
        }
        #pragma unroll
        for (int i = 0; i < MH2; ++i) {
            int r = wr * (BM / WM) + i * 16 + fr;
            int es = fq ^ ((r >> 1) & 3);
            afL[i] = *(const f16x8*)&as1[r * 32 + es * 8];
        }
        if (s0 + 4 < NS) stageA(s0 + 4);
        __builtin_amdgcn_s_barrier();
        waitlgkm0();
        __builtin_amdgcn_sched_barrier(0);
        __builtin_amdgcn_s_setprio(1);
        #pragma unroll
        for (int i = 0; i < MH2; ++i)
            #pragma unroll
            for (int n = 0; n < NR; ++n)
                acc[i][n] = __builtin_amdgcn_mfma_f32_16x16x32_f16(afL[i], bf[n], acc[i][n], 0, 0, 0);
        __builtin_amdgcn_s_setprio(0);
        __builtin_amdgcn_s_barrier();

        // ---------- ph3: kk1, m-rows [MH2, MR) ----------
        #pragma unroll
        for (int i = 0; i < MH2; ++i) {
            int r = wr * (BM / WM) + (MH2 + i) * 16 + fr;
            int es = fq ^ ((r >> 1) & 3);
            afH[i] = *(const f16x8*)&as1[r * 32 + es * 8];
        }
        if (s0 + 4 < NS) stageB(s0 + 4);
        __builtin_amdgcn_s_barrier();
        waitlgkm0();
        __builtin_amdgcn_sched_barrier(0);
        __builtin_amdgcn_s_setprio(1);
        #pragma unroll
        for (int i = 0; i < MH2; ++i)
            #pragma unroll
            for (int n = 0; n < NR; ++n)
                acc[MH2 + i][n] = __builtin_amdgcn_mfma_f32_16x16x32_f16(afH[i], bf[n], acc[MH2 + i][n], 0, 0, 0);
        __builtin_amdgcn_s_setprio(0);
        if (t < NT - 2) waitvm<SN>();       // drain (t+1,Ak0),(t+1,Bk0)
        else if (t == NT - 2) waitvm<TN>();
        __builtin_amdgcn_s_barrier();
    }

    // epilogue: C/D layout col=lane&15, row=(lane>>4)*4+i
    const int row0 = by * BM + wr * (BM / WM);
    const int col0 = bx * BN + wc * (BN / WN);
    #pragma unroll
    for (int m = 0; m < MR; ++m)
        #pragma unroll
        for (int n = 0; n < NR; ++n)
            #pragma unroll
            for (int i = 0; i < 4; ++i) {
                int r = row0 + m * 16 + fq * 4 + i;
                int c = col0 + n * 16 + fr;
                float v = acc[m][n][i];
                if constexpr (BIAS_MODE == 1) v += bias[c];
                if constexpr (BIAS_MODE == 2) v += bias[r];
                if constexpr (OUT_F16)
                    ((unsigned short*)Cptr + bz * cBatch)[(long long)r * ldc + c] = f2h_bits(v);
                else
                    ((float*)Cptr + bz * cBatch)[(long long)r * ldc + c] = v;
            }
}

// ===================== small kernels =====================
__global__ __launch_bounds__(256) void cvt_f32_f16(const float* __restrict__ in,
                                                   unsigned short* __restrict__ out, int n8)
{
    int i = blockIdx.x * blockDim.x + threadIdx.x;
    if (i >= n8) return;
    const float4* p = (const float4*)in + (long long)i * 2;
    float4 a = p[0], b = p[1];
    ushort4 o0, o1;
    o0.x = f2h_bits(a.x); o0.y = f2h_bits(a.y); o0.z = f2h_bits(a.z); o0.w = f2h_bits(a.w);
    o1.x = f2h_bits(b.x); o1.y = f2h_bits(b.y); o1.z = f2h_bits(b.z); o1.w = f2h_bits(b.w);
    ushort4* o = (ushort4*)out + (long long)i * 2;
    o[0] = o0; o[1] = o1;
}

__global__ void transpose_cvt(const float* __restrict__ in, unsigned short* __restrict__ out,
                              int R, int C)
{
    __shared__ unsigned short t[32][33];
    const int bx = blockIdx.x * 32;
    const int by = blockIdx.y * 32;
    const int xT = threadIdx.x, yT = threadIdx.y;  // block (32,8)
    #pragma unroll
    for (int i = 0; i < 32; i += 8)
        t[yT + i][xT] = f2h_bits(in[(long long)(by + yT + i) * C + bx + xT]);
    __syncthreads();
    #pragma unroll
    for (int i = 0; i < 32; i += 8)
        out[(long long)(bx + yT + i) * R + by + xT] = t[xT][yT + i];
}

__global__ void concat_bias2(const float* __restrict__ bq, const float* __restrict__ bk,
                             float* __restrict__ cb)
{
    int i = threadIdx.x;  // 1024 threads
    cb[i] = bq[i];
    cb[HIDDEN + i] = bk[i];
}

// One block (256 threads) per row of 2048 fp16 scores; P fp16 in place.
__global__ __launch_bounds__(256) void softmax_h(unsigned short* __restrict__ S)
{
    const int tid = threadIdx.x;
    unsigned short* row = S + (long long)blockIdx.x * SEQ;
    u16x8 hv = *(const u16x8*)&row[tid * 8];
    float vv[8];
    #pragma unroll
    for (int j = 0; j < 8; ++j) vv[j] = h2f(hv[j]);

    float mx = vv[0];
    #pragma unroll
    for (int j = 1; j < 8; ++j) mx = fmaxf(mx, vv[j]);
    #pragma unroll
    for (int o = 32; o > 0; o >>= 1) mx = fmaxf(mx, __shfl_xor(mx, o));
    __shared__ float redm[4], reds[4];
    if ((tid & 63) == 0) redm[tid >> 6] = mx;
    __syncthreads();
    mx = fmaxf(fmaxf(redm[0], redm[1]), fmaxf(redm[2], redm[3]));

    float ev[8], sum = 0.f;
    #pragma unroll
    for (int j = 0; j < 8; ++j) { ev[j] = __expf(vv[j] - mx); sum += ev[j]; }
    #pragma unroll
    for (int o = 32; o > 0; o >>= 1) sum += __shfl_xor(sum, o);
    if ((tid & 63) == 0) reds[tid >> 6] = sum;
    __syncthreads();
    sum = reds[0] + reds[1] + reds[2] + reds[3];
    float inv = 1.0f / sum;

    u16x8 ov;
    #pragma unroll
    for (int j = 0; j < 8; ++j) ov[j] = f2h_bits(ev[j] * inv);
    *(u16x8*)&row[tid * 8] = ov;
}

// ===================== launch =====================
extern "C" void kernel_launch(void* const* d_in, const int* in_sizes, int n_in,
                              void* d_out, int out_size, void* d_ws, size_t ws_size,
                              hipStream_t stream)
{
    (void)in_sizes; (void)n_in; (void)out_size; (void)ws_size;
    const float* x  = (const float*)d_in[0];
    const float* Wq = (const float*)d_in[1];
    const float* bq = (const float*)d_in[2];
    const float* Wk = (const float*)d_in[3];
    const float* bk = (const float*)d_in[4];
    const float* Wv = (const float*)d_in[5];
    const float* bv = (const float*)d_in[6];
    float* out = (float*)d_out;

    // variants: proj/S 256x256 (8 waves, 128KB); vt 128x256 (96KB); O 256x128 (96KB)
    (void)hipFuncSetAttribute(reinterpret_cast<const void*>(&gemm4p<256, 256, 2, 4, 1, true>),
                              hipFuncAttributeMaxDynamicSharedMemorySize, 131072);
    (void)hipFuncSetAttribute(reinterpret_cast<const void*>(&gemm4p<256, 256, 2, 4, 0, true>),
                              hipFuncAttributeMaxDynamicSharedMemorySize, 131072);
    (void)hipFuncSetAttribute(reinterpret_cast<const void*>(&gemm4p<128, 256, 2, 4, 2, true>),
                              hipFuncAttributeMaxDynamicSharedMemorySize, 98304);
    (void)hipFuncSetAttribute(reinterpret_cast<const void*>(&gemm4p<256, 128, 2, 4, 0, false>),
                              hipFuncAttributeMaxDynamicSharedMemorySize, 98304);

    char* ws = (char*)d_ws;
    const long long MTOT = (long long)NB * SEQ;  // 8192

    // Layout (83.9 MB):
    //  [0, 33.55M)      qk   [8192][2048] fp16
    //  [33.55, 50.33M)  vt   [1024][8192] fp16
    //  [50.33, 83.89M)  S region: 4 x [2048][2048] fp16 (all batches).
    //    During projections it holds wt (6.29M) + cb + xh (16.78M), dead after vt.
    unsigned short* qk = (unsigned short*)ws;
    unsigned short* vt = (unsigned short*)(ws + (size_t)MTOT * 2048 * 2);
    char* sreg = ws + (size_t)MTOT * 2048 * 2 + (size_t)HIDDEN * MTOT * 2;
    unsigned short* wt = (unsigned short*)sreg;
    float* cb = (float*)(sreg + (size_t)3 * HIDDEN * HIDDEN * 2);
    unsigned short* xh = (unsigned short*)(sreg + (size_t)3 * HIDDEN * HIDDEN * 2 + 8192);
    unsigned short* S = (unsigned short*)sreg;

    {
        int n8 = (int)(MTOT * HIDDEN / 8);
        cvt_f32_f16<<<dim3((n8 + 255) / 256), 256, 0, stream>>>(x, xh, n8);
    }
    dim3 tb(32, 8), tg(HIDDEN / 32, HIDDEN / 32);
    transpose_cvt<<<tg, tb, 0, stream>>>(Wq, wt,                       HIDDEN, HIDDEN);
    transpose_cvt<<<tg, tb, 0, stream>>>(Wk, wt +     HIDDEN * HIDDEN, HIDDEN, HIDDEN);
    transpose_cvt<<<tg, tb, 0, stream>>>(Wv, wt + 2 * HIDDEN * HIDDEN, HIDDEN, HIDDEN);
    concat_bias2<<<1, 1024, 0, stream>>>(bq, bk, cb);

    // qk[8192][2048] = xh @ [Wq|Wk] + [bq|bk]   (256 blocks)
    gemm4p<256, 256, 2, 4, 1, true><<<dim3(2048 / 256, (unsigned)(MTOT / 256), 1), 512, 131072, stream>>>(
        xh, HIDDEN, wt, HIDDEN, cb, qk, 2048, HIDDEN, 0, 0, 0);

    // vt[1024][8192] = Wv^T @ xh^T + bv (row bias)   (256 blocks)
    gemm4p<128, 256, 2, 4, 2, true><<<dim3((unsigned)(MTOT / 256), HIDDEN / 128, 1), 512, 98304, stream>>>(
        wt + 2 * HIDDEN * HIDDEN, HIDDEN, xh, HIDDEN, bv, vt, (int)MTOT, HIDDEN, 0, 0, 0);

    // S[b][2048][2048] fp16 = q @ k^T   (z=4, 256 blocks)
    gemm4p<256, 256, 2, 4, 0, true><<<dim3(SEQ / 256, SEQ / 256, NB), 512, 131072, stream>>>(
        qk, 2048, qk + HIDDEN, 2048, nullptr, S, SEQ, HIDDEN,
        (long long)SEQ * 2048, (long long)SEQ * 2048, (long long)SEQ * SEQ);

    // softmax all rows, P fp16 in place
    softmax_h<<<dim3(NB * SEQ), 256, 0, stream>>>(S);

    // out[b] = P @ vt^T  (z=4, 256 blocks, f32 straight to d_out)
    gemm4p<256, 128, 2, 4, 0, false><<<dim3(HIDDEN / 128, SEQ / 256, NB), 512, 98304, stream>>>(
        S, SEQ, vt, (int)MTOT, nullptr, out, HIDDEN, SEQ,
        (long long)SEQ * SEQ, (long long)SEQ, (long long)SEQ * HIDDEN);
}

// Round 13
// 169.066 us; speedup vs baseline: 1.1104x; 1.0694x over previous
//
#include <hip/hip_runtime.h>
#include <stdint.h>

typedef __attribute__((ext_vector_type(4))) float f32x4;
typedef __attribute__((ext_vector_type(8))) _Float16 f16x8;
typedef __attribute__((ext_vector_type(8))) unsigned short u16x8;

#define HIDDEN 1024
#define SEQ 2048
#define NB 4

__device__ inline unsigned short f2h_bits(float f) {
    _Float16 h = (_Float16)f;
    return __builtin_bit_cast(unsigned short, h);
}
__device__ inline float h2f(unsigned short u) {
    return (float)__builtin_bit_cast(_Float16, u);
}

__device__ inline void gload16(const void* g, void* l) {
    __builtin_amdgcn_global_load_lds(
        (const __attribute__((address_space(1))) unsigned int*)g,
        (__attribute__((address_space(3))) unsigned int*)l,
        16, 0, 0);
}

template<int N> __device__ inline void waitvm() {
    if constexpr (N == 0) asm volatile("s_waitcnt vmcnt(0)" ::: "memory");
    else if constexpr (N == 3) asm volatile("s_waitcnt vmcnt(3)" ::: "memory");
    else if constexpr (N == 4) asm volatile("s_waitcnt vmcnt(4)" ::: "memory");
    else if constexpr (N == 6) asm volatile("s_waitcnt vmcnt(6)" ::: "memory");
    else if constexpr (N == 8) asm volatile("s_waitcnt vmcnt(8)" ::: "memory");
    else static_assert(N == 0, "bad vmcnt");
}

// ============ R7-structure GEMM, compiler-scheduled LDS path ============
// C[M,N] = A[M,K] @ Bt[N,K]^T (+bias). fp16 in, f32 accum.
// Wave grid WM x WN; wave tile (BM/WM) x (BN/WN). K in 32-slices; slice-major
// LDS ring of 4 slots; swizzle phys-16B-slot = logical ^ ((row>>1)&3)
// (0 conflicts, verified R4-R12). Stage distance 3; counted vmcnt gate at the
// top of each slice (2LP steady, LP/0 tail) — the one thing the compiler
// cannot derive. Everything else (lgkm waits, MFMA interleave) is left to
// the compiler, which emits fine-grained lgkmcnt(4/3/1/0) (m97: 874-912 TF).
// No setprio (m190: harmful on lockstep GEMM), no sched_barrier pinning
// (m141: defeats compiler scheduling). A zero-cost compiler fence after each
// barrier stops LDS reads from hoisting above it (WAR/RAW proof as in R7).
// T1: bijective XCD block swizzle (requires nwg % 8 == 0).
// BIAS_MODE: 0 none, 1 bias[col], 2 bias[row].
template<int BM, int BN, int WM, int WN, int BIAS_MODE, bool OUT_F16, int MINW>
__global__ __launch_bounds__(WM * WN * 64, MINW) void gemm8p(
    const unsigned short* __restrict__ A, int lda,
    const unsigned short* __restrict__ Bt, int ldb,
    const float* __restrict__ bias,
    void* __restrict__ Cptr, int ldc, int K,
    long long aBatch, long long bBatch, long long cBatch)
{
    constexpr int THREADS = WM * WN * 64;
    constexpr int MR = BM / (WM * 16);
    constexpr int NRW = BN / (WN * 16);
    constexpr int LA = 4 * BM / THREADS;
    constexpr int LB = 4 * BN / THREADS;
    constexpr int LP = LA + LB;
    constexpr int ASLICE = BM * 32;
    constexpr int BSLICE = BN * 32;
    constexpr int BOFF = 4 * ASLICE;

    extern __shared__ unsigned short lds[];

    const int tid = threadIdx.x, lane = tid & 63, wave = tid >> 6;
    const int wr = wave / WN, wc = wave % WN;
    const int fr = lane & 15, fq = lane >> 4;

    // T1 XCD-bijective block swizzle over the flat grid
    const int gx = gridDim.x, gy = gridDim.y;
    const int nwg = gx * gy * gridDim.z;
    const int id = (blockIdx.z * gy + blockIdx.y) * gx + blockIdx.x;
    const int id2 = (id & 7) * (nwg >> 3) + (id >> 3);
    const int bx = id2 % gx;
    const int by = (id2 / gx) % gy;
    const long long bz = id2 / (gx * gy);

    const unsigned short* Ab = A + bz * aBatch + (long long)(by * BM) * lda;
    const unsigned short* Bb = Bt + bz * bBatch + (long long)(bx * BN) * ldb;

    // staging: chunk c = i*THREADS+tid; row=c>>2, phys slot=c&3,
    // logical slot = phys ^ ((row>>1)&3) -> pre-inverse-swizzled source
    const unsigned short* sA[LA]; int dA[LA];
    #pragma unroll
    for (int i = 0; i < LA; ++i) {
        int c = i * THREADS + tid; int r = c >> 2; int ls = (c & 3) ^ ((r >> 1) & 3);
        sA[i] = Ab + (long long)r * lda + ls * 8;
        dA[i] = (i * THREADS + wave * 64) * 16;
    }
    const unsigned short* sB[LB]; int dB[LB];
    #pragma unroll
    for (int i = 0; i < LB; ++i) {
        int c = i * THREADS + tid; int r = c >> 2; int ls = (c & 3) ^ ((r >> 1) & 3);
        sB[i] = Bb + (long long)r * ldb + ls * 8;
        dB[i] = (i * THREADS + wave * 64) * 16;
    }

    auto stage = [&](int q) {   // stage slice q -> ring slot q&3
        int slot = q & 3, kof = q * 32;
        #pragma unroll
        for (int i = 0; i < LA; ++i)
            gload16(sA[i] + kof, (char*)lds + slot * (ASLICE * 2) + dA[i]);
        #pragma unroll
        for (int i = 0; i < LB; ++i)
            gload16(sB[i] + kof, (char*)lds + (BOFF + slot * BSLICE) * 2 + dB[i]);
    };

    const int NPAIR = K / 32;
    stage(0); stage(1); stage(2);    // 3 slices in flight

    f32x4 acc[MR][NRW] = {};

    for (int p = 0; p < NPAIR; ++p) {
        // gate: slice p landed; slices p+1,p+2 stay in flight
        if (p == NPAIR - 1) waitvm<0>();
        else if (p == NPAIR - 2) waitvm<LP>();
        else waitvm<2 * LP>();
        __builtin_amdgcn_s_barrier();
        asm volatile("" ::: "memory");     // compiler fence only: no reads hoist

        const int slot = p & 3;
        const unsigned short* as = lds + slot * ASLICE;
        const unsigned short* bs = lds + BOFF + slot * BSLICE;

        f16x8 af[MR], bf[NRW];
        #pragma unroll
        for (int n = 0; n < NRW; ++n) {
            int r = wc * (BN / WN) + n * 16 + fr;
            int es = fq ^ ((r >> 1) & 3);
            bf[n] = *(const f16x8*)&bs[r * 32 + es * 8];
        }
        #pragma unroll
        for (int m = 0; m < MR; ++m) {
            int r = wr * (BM / WM) + m * 16 + fr;
            int es = fq ^ ((r >> 1) & 3);
            af[m] = *(const f16x8*)&as[r * 32 + es * 8];
        }
        if (p + 3 < NPAIR) stage(p + 3);   // slot (p+3)&3 == (p-1)&3: its readers
                                           // completed before this slice's barrier
        // MFMA burst; compiler inserts fine-grained lgkm waits and interleaves
        #pragma unroll
        for (int m = 0; m < MR; ++m)
            #pragma unroll
            for (int n = 0; n < NRW; ++n)
                acc[m][n] = __builtin_amdgcn_mfma_f32_16x16x32_f16(af[m], bf[n], acc[m][n], 0, 0, 0);
    }

    // epilogue: C/D layout col=lane&15, row=(lane>>4)*4+i
    const int row0 = by * BM + wr * (BM / WM);
    const int col0 = bx * BN + wc * (BN / WN);
    #pragma unroll
    for (int m = 0; m < MR; ++m)
        #pragma unroll
        for (int n = 0; n < NRW; ++n)
            #pragma unroll
            for (int i = 0; i < 4; ++i) {
                int r = row0 + m * 16 + fq * 4 + i;
                int c = col0 + n * 16 + fr;
                float v = acc[m][n][i];
                if constexpr (BIAS_MODE == 1) v += bias[c];
                if constexpr (BIAS_MODE == 2) v += bias[r];
                if constexpr (OUT_F16)
                    ((unsigned short*)Cptr + bz * cBatch)[(long long)r * ldc + c] = f2h_bits(v);
                else
                    ((float*)Cptr + bz * cBatch)[(long long)r * ldc + c] = v;
            }
}

// ===================== small kernels =====================
__global__ __launch_bounds__(256) void cvt_f32_f16(const float* __restrict__ in,
                                                   unsigned short* __restrict__ out, int n8)
{
    int i = blockIdx.x * blockDim.x + threadIdx.x;
    if (i >= n8) return;
    const float4* p = (const float4*)in + (long long)i * 2;
    float4 a = p[0], b = p[1];
    ushort4 o0, o1;
    o0.x = f2h_bits(a.x); o0.y = f2h_bits(a.y); o0.z = f2h_bits(a.z); o0.w = f2h_bits(a.w);
    o1.x = f2h_bits(b.x); o1.y = f2h_bits(b.y); o1.z = f2h_bits(b.z); o1.w = f2h_bits(b.w);
    ushort4* o = (ushort4*)out + (long long)i * 2;
    o[0] = o0; o[1] = o1;
}

// z in {0,1,2} picks (Wq,Wk,Wv); out[z][c][r] = (fp16) W[r][c]
__global__ void transpose_cvt3(const float* __restrict__ W0, const float* __restrict__ W1,
                               const float* __restrict__ W2, unsigned short* __restrict__ out)
{
    __shared__ unsigned short t[32][33];
    const int z = blockIdx.z;
    const float* in = (z == 0) ? W0 : (z == 1) ? W1 : W2;
    unsigned short* o = out + (long long)z * HIDDEN * HIDDEN;
    const int bx = blockIdx.x * 32;
    const int by = blockIdx.y * 32;
    const int xT = threadIdx.x, yT = threadIdx.y;  // block (32,8)
    #pragma unroll
    for (int i = 0; i < 32; i += 8)
        t[yT + i][xT] = f2h_bits(in[(long long)(by + yT + i) * HIDDEN + bx + xT]);
    __syncthreads();
    #pragma unroll
    for (int i = 0; i < 32; i += 8)
        o[(long long)(bx + yT + i) * HIDDEN + by + xT] = t[xT][yT + i];
}

__global__ void concat_bias2(const float* __restrict__ bq, const float* __restrict__ bk,
                             float* __restrict__ cb)
{
    int i = threadIdx.x;  // 1024 threads
    cb[i] = bq[i];
    cb[HIDDEN + i] = bk[i];
}

// One block (256 threads) per row of 2048 fp16 scores; P fp16 in place.
__global__ __launch_bounds__(256) void softmax_h(unsigned short* __restrict__ S)
{
    const int tid = threadIdx.x;
    unsigned short* row = S + (long long)blockIdx.x * SEQ;
    u16x8 hv = *(const u16x8*)&row[tid * 8];
    float vv[8];
    #pragma unroll
    for (int j = 0; j < 8; ++j) vv[j] = h2f(hv[j]);

    float mx = vv[0];
    #pragma unroll
    for (int j = 1; j < 8; ++j) mx = fmaxf(mx, vv[j]);
    #pragma unroll
    for (int o = 32; o > 0; o >>= 1) mx = fmaxf(mx, __shfl_xor(mx, o));
    __shared__ float redm[4], reds[4];
    if ((tid & 63) == 0) redm[tid >> 6] = mx;
    __syncthreads();
    mx = fmaxf(fmaxf(redm[0], redm[1]), fmaxf(redm[2], redm[3]));

    float ev[8], sum = 0.f;
    #pragma unroll
    for (int j = 0; j < 8; ++j) { ev[j] = __expf(vv[j] - mx); sum += ev[j]; }
    #pragma unroll
    for (int o = 32; o > 0; o >>= 1) sum += __shfl_xor(sum, o);
    if ((tid & 63) == 0) reds[tid >> 6] = sum;
    __syncthreads();
    sum = reds[0] + reds[1] + reds[2] + reds[3];
    float inv = 1.0f / sum;

    u16x8 ov;
    #pragma unroll
    for (int j = 0; j < 8; ++j) ov[j] = f2h_bits(ev[j] * inv);
    *(u16x8*)&row[tid * 8] = ov;
}

// ===================== launch =====================
extern "C" void kernel_launch(void* const* d_in, const int* in_sizes, int n_in,
                              void* d_out, int out_size, void* d_ws, size_t ws_size,
                              hipStream_t stream)
{
    (void)in_sizes; (void)n_in; (void)out_size; (void)ws_size;
    const float* x  = (const float*)d_in[0];
    const float* Wq = (const float*)d_in[1];
    const float* bq = (const float*)d_in[2];
    const float* Wk = (const float*)d_in[3];
    const float* bk = (const float*)d_in[4];
    const float* Wv = (const float*)d_in[5];
    const float* bv = (const float*)d_in[6];
    float* out = (float*)d_out;

    // variants: proj/S 256x256 (8 waves, 128KB); vt 128x256 (96KB); O 256x128 (96KB)
    (void)hipFuncSetAttribute(reinterpret_cast<const void*>(&gemm8p<256, 256, 2, 4, 1, true, 2>),
                              hipFuncAttributeMaxDynamicSharedMemorySize, 131072);
    (void)hipFuncSetAttribute(reinterpret_cast<const void*>(&gemm8p<256, 256, 2, 4, 0, true, 2>),
                              hipFuncAttributeMaxDynamicSharedMemorySize, 131072);
    (void)hipFuncSetAttribute(reinterpret_cast<const void*>(&gemm8p<128, 256, 2, 4, 2, true, 2>),
                              hipFuncAttributeMaxDynamicSharedMemorySize, 98304);
    (void)hipFuncSetAttribute(reinterpret_cast<const void*>(&gemm8p<256, 128, 2, 4, 0, false, 2>),
                              hipFuncAttributeMaxDynamicSharedMemorySize, 98304);

    char* ws = (char*)d_ws;
    const long long MTOT = (long long)NB * SEQ;  // 8192

    // Layout (83.9 MB):
    //  [0, 33.55M)      qk   [8192][2048] fp16
    //  [33.55, 50.33M)  vt   [1024][8192] fp16
    //  [50.33, 83.89M)  S region: 4 x [2048][2048] fp16 (all batches).
    //    During projections it holds wt (6.29M) + cb + xh (16.78M), dead after vt.
    unsigned short* qk = (unsigned short*)ws;
    unsigned short* vt = (unsigned short*)(ws + (size_t)MTOT * 2048 * 2);
    char* sreg = ws + (size_t)MTOT * 2048 * 2 + (size_t)HIDDEN * MTOT * 2;
    unsigned short* wt = (unsigned short*)sreg;
    float* cb = (float*)(sreg + (size_t)3 * HIDDEN * HIDDEN * 2);
    unsigned short* xh = (unsigned short*)(sreg + (size_t)3 * HIDDEN * HIDDEN * 2 + 8192);
    unsigned short* S = (unsigned short*)sreg;

    {
        int n8 = (int)(MTOT * HIDDEN / 8);
        cvt_f32_f16<<<dim3((n8 + 255) / 256), 256, 0, stream>>>(x, xh, n8);
    }
    dim3 tb(32, 8);
    transpose_cvt3<<<dim3(HIDDEN / 32, HIDDEN / 32, 3), tb, 0, stream>>>(Wq, Wk, Wv, wt);
    concat_bias2<<<1, 1024, 0, stream>>>(bq, bk, cb);

    // qk[8192][2048] = xh @ [Wq|Wk] + [bq|bk]   (256 blocks)
    gemm8p<256, 256, 2, 4, 1, true, 2><<<dim3(2048 / 256, (unsigned)(MTOT / 256), 1), 512, 131072, stream>>>(
        xh, HIDDEN, wt, HIDDEN, cb, qk, 2048, HIDDEN, 0, 0, 0);

    // vt[1024][8192] = Wv^T @ xh^T + bv (row bias)   (256 blocks)
    gemm8p<128, 256, 2, 4, 2, true, 2><<<dim3((unsigned)(MTOT / 256), HIDDEN / 128, 1), 512, 98304, stream>>>(
        wt + 2 * HIDDEN * HIDDEN, HIDDEN, xh, HIDDEN, bv, vt, (int)MTOT, HIDDEN, 0, 0, 0);

    // S[b][2048][2048] fp16 = q @ k^T   (z=4, 256 blocks)
    gemm8p<256, 256, 2, 4, 0, true, 2><<<dim3(SEQ / 256, SEQ / 256, NB), 512, 131072, stream>>>(
        qk, 2048, qk + HIDDEN, 2048, nullptr, S, SEQ, HIDDEN,
        (long long)SEQ * 2048, (long long)SEQ * 2048, (long long)SEQ * SEQ);

    // softmax all rows, P fp16 in place
    softmax_h<<<dim3(NB * SEQ), 256, 0, stream>>>(S);

    // out[b] = P @ vt^T  (z=4, 512 blocks, f32 straight to d_out)
    gemm8p<256, 128, 2, 4, 0, false, 2><<<dim3(HIDDEN / 128, SEQ / 256, NB), 512, 98304, stream>>>(
        S, SEQ, vt, (int)MTOT, nullptr, out, HIDDEN, SEQ,
        (long long)SEQ * SEQ, (long long)SEQ, (long long)SEQ * HIDDEN);
}